// Round 2
// baseline (168.011 us; speedup 1.0000x reference)
//
#include <hip/hip_runtime.h>
#include <hip/hip_bf16.h>
#include <cstddef>

// Problem constants (reference: B=128, IN=1024, H=1024, TAU=1.0)
#define B_DIM  128
#define IN_DIM 1024
#define H_DIM  1024

constexpr float kDecay   = 1.0f - 0.01f;    // 1 - FAST_WEIGHT_DECAY
constexpr float kLrOverB = 0.01f / 128.0f;  // FAST_WEIGHT_LR / B

// ---------------------------------------------------------------------------
// Kernel 0: ic[b][o] = x_t[b,:] . W_ih[o,:] + b_ih[o]     (268 MFLOP GEMM)
//   grid = (H/64, B/16), block = 256. Tiles: o=64, b=16, k=64 staged in LDS
//   (both transposed to [k][...] for conflict-free inner-loop reads).
// ---------------------------------------------------------------------------
__global__ __launch_bounds__(256) void input_gemm(
    const float* __restrict__ x_t,   // (B, IN)
    const float* __restrict__ W_ih,  // (H, IN)
    const float* __restrict__ b_ih,  // (H,)
    float* __restrict__ ic)          // (B, H)  [workspace]
{
    const int o0 = blockIdx.x * 64;
    const int b0 = blockIdx.y * 16;
    const int t  = threadIdx.x;

    __shared__ float Wt[64][68];   // [k][o], pad 68 keeps rows 16B-aligned
    __shared__ float xs[64][17];   // [k][b]

    const int tx = t & 15;         // o group: 4 outputs at o0 + 4*tx
    const int ty = t >> 4;         // b: b0 + ty

    float acc[4] = {0.f, 0.f, 0.f, 0.f};

    for (int kc = 0; kc < IN_DIM / 64; ++kc) {
        const int k0 = kc * 64;

#pragma unroll
        for (int ii = 0; ii < 4; ++ii) {
            const int i  = t + 256 * ii;      // float4 tile index 0..1023
            const int r  = i >> 4;            // o row 0..63
            const int c4 = (i & 15) * 4;      // k col 0..60
            const float4 wv = *reinterpret_cast<const float4*>(
                &W_ih[(size_t)(o0 + r) * IN_DIM + k0 + c4]);
            Wt[c4 + 0][r] = wv.x; Wt[c4 + 1][r] = wv.y;
            Wt[c4 + 2][r] = wv.z; Wt[c4 + 3][r] = wv.w;
        }
        {
            const int br = t >> 4;            // b row 0..15
            const int c4 = (t & 15) * 4;      // k col
            const float4 xv = *reinterpret_cast<const float4*>(
                &x_t[(size_t)(b0 + br) * IN_DIM + k0 + c4]);
            xs[c4 + 0][br] = xv.x; xs[c4 + 1][br] = xv.y;
            xs[c4 + 2][br] = xv.z; xs[c4 + 3][br] = xv.w;
        }
        __syncthreads();

#pragma unroll 8
        for (int k = 0; k < 64; ++k) {
            const float  xb = xs[k][ty];
            const float4 wv = *reinterpret_cast<const float4*>(&Wt[k][4 * tx]);
            acc[0] = fmaf(wv.x, xb, acc[0]);
            acc[1] = fmaf(wv.y, xb, acc[1]);
            acc[2] = fmaf(wv.z, xb, acc[2]);
            acc[3] = fmaf(wv.w, xb, acc[3]);
        }
        __syncthreads();
    }

    const int o = o0 + 4 * tx;
    const int b = b0 + ty;
    float4 r;
    r.x = acc[0] + b_ih[o + 0];
    r.y = acc[1] + b_ih[o + 1];
    r.z = acc[2] + b_ih[o + 2];
    r.w = acc[3] + b_ih[o + 3];
    *reinterpret_cast<float4*>(&ic[(size_t)b * H_DIM + o]) = r;
}

// ---------------------------------------------------------------------------
// Kernel A: gumbel-softmax exchange + tanh, single pass over gumbel_u.
//   Identity: exp(logit + g) = exp(logit) * 1/(-log u)  (TAU = 1), and the
//   dot/sum ratio is max-shift invariant (terms <= ~2e7, sum <= ~2e10: fp32 ok)
//   -> one pass, no max reduction, no register row buffers.
//   grid = (H/8, B/8), block = 512 (8 waves). Block (oc, bc):
//     LDS: el[8][1024] = exp(W_f+W_v) rows (staged once per block).
//     wave w owns b = bc*8+w: h_prev row lives in 16 regs for all 8 o-rows.
// ---------------------------------------------------------------------------
__global__ __launch_bounds__(512, 4) void fused_rows(
    const float* __restrict__ h_prev,  // (B, H)
    const float* __restrict__ W_f,     // (H, H)
    const float* __restrict__ W_v,     // (H, H)
    const float* __restrict__ gu,      // (B, H, H)
    const float* __restrict__ ic,      // (B, H)  [workspace, bias included]
    float* __restrict__ h_next)        // (B, H)  [= d_out region 0]
{
    const int o0 = blockIdx.x * 8;
    const int b0 = blockIdx.y * 8;
    const int t  = threadIdx.x;

    __shared__ __align__(16) float el[8 * H_DIM];  // 32 KB

    // Stage exp(W_f + W_v) for rows o0..o0+7 (512 threads x 4 float4).
#pragma unroll
    for (int ii = 0; ii < 4; ++ii) {
        const int i = t + 512 * ii;     // float4 index 0..2047
        const int r = i >> 8;           // row 0..7
        const int c = i & 255;          // float4 col
        const size_t off = (size_t)(o0 + r) * H_DIM + 4 * c;
        const float4 a = *reinterpret_cast<const float4*>(W_f + off);
        const float4 b = *reinterpret_cast<const float4*>(W_v + off);
        float4 e;
        e.x = __expf(a.x + b.x); e.y = __expf(a.y + b.y);
        e.z = __expf(a.z + b.z); e.w = __expf(a.w + b.w);
        reinterpret_cast<float4*>(el)[i] = e;
    }
    __syncthreads();

    const int w = t >> 6, lane = t & 63;
    const int b = b0 + w;

    // h_prev row -> 16 registers, reused for all 8 o-rows.
    const float4* hp4 = reinterpret_cast<const float4*>(h_prev + (size_t)b * H_DIM);
    float4 hp[4];
#pragma unroll
    for (int j = 0; j < 4; ++j) hp[j] = hp4[lane + 64 * j];

    const float4* el4 = reinterpret_cast<const float4*>(el);

#pragma unroll 2
    for (int oi = 0; oi < 8; ++oi) {
        const int o = o0 + oi;
        const float4* g4 =
            reinterpret_cast<const float4*>(gu + ((size_t)b * H_DIM + o) * H_DIM);

        float sum = 0.f, dot = 0.f;
#pragma unroll
        for (int j = 0; j < 4; ++j) {
            const float4 u = g4[lane + 64 * j];
            const float4 e = el4[oi * 256 + lane + 64 * j];
            const float4 p = hp[j];

            const float t0 = -__logf(fmaxf(u.x, 1e-9f));
            const float t1 = -__logf(fmaxf(u.y, 1e-9f));
            const float t2 = -__logf(fmaxf(u.z, 1e-9f));
            const float t3 = -__logf(fmaxf(u.w, 1e-9f));
            const float q0 = __fdividef(e.x, t0);
            const float q1 = __fdividef(e.y, t1);
            const float q2 = __fdividef(e.z, t2);
            const float q3 = __fdividef(e.w, t3);
            sum += q0 + q1 + q2 + q3;
            dot = fmaf(q0, p.x, dot);
            dot = fmaf(q1, p.y, dot);
            dot = fmaf(q2, p.z, dot);
            dot = fmaf(q3, p.w, dot);
        }

#pragma unroll
        for (int off = 32; off > 0; off >>= 1) {
            sum += __shfl_xor(sum, off, 64);
            dot += __shfl_xor(dot, off, 64);
        }

        if (lane == 0) {
            h_next[(size_t)b * H_DIM + o] =
                tanhf(ic[(size_t)b * H_DIM + o] + dot / sum);
        }
    }
}

// ---------------------------------------------------------------------------
// Kernel B: W_out = 0.99 * W_v + (0.01/B) * (h_next^T @ h_prev)   (unchanged)
// ---------------------------------------------------------------------------
__global__ __launch_bounds__(256) void hebbian_update(
    const float* __restrict__ h_next,  // (B, H)
    const float* __restrict__ h_prev,  // (B, H)
    const float* __restrict__ W_v,     // (H, H)
    float* __restrict__ W_out)         // (H, H)  [= d_out region 1]
{
    const int h0 = blockIdx.x * 64;
    const int o0 = blockIdx.y * 64;
    const int t  = threadIdx.x;

    __shared__ __align__(16) float hn_s[B_DIM][64];  // 32 KB
    __shared__ __align__(16) float hp_s[B_DIM][64];  // 32 KB

#pragma unroll
    for (int i = 0; i < 32; ++i) {
        const int e  = t + 256 * i;
        const int bb = e >> 6;
        const int cc = e & 63;
        hn_s[bb][cc] = h_next[(size_t)bb * H_DIM + o0 + cc];
        hp_s[bb][cc] = h_prev[(size_t)bb * H_DIM + h0 + cc];
    }
    __syncthreads();

    const int tx = t & 15;   // h group
    const int ty = t >> 4;   // o group

    float acc[4][4] = {{0.f}};

#pragma unroll 8
    for (int b = 0; b < B_DIM; ++b) {
        const float4 av = reinterpret_cast<const float4*>(hn_s[b])[ty];
        const float4 bv = reinterpret_cast<const float4*>(hp_s[b])[tx];
        const float aa[4] = {av.x, av.y, av.z, av.w};
        const float bb[4] = {bv.x, bv.y, bv.z, bv.w};
#pragma unroll
        for (int a = 0; a < 4; ++a)
#pragma unroll
            for (int c = 0; c < 4; ++c)
                acc[a][c] = fmaf(aa[a], bb[c], acc[a][c]);
    }

#pragma unroll
    for (int a = 0; a < 4; ++a) {
        const int o = o0 + 4 * ty + a;
        const size_t base = (size_t)o * H_DIM + h0 + 4 * tx;
        const float4 wv = *reinterpret_cast<const float4*>(W_v + base);
        float4 r;
        r.x = wv.x * kDecay + acc[a][0] * kLrOverB;
        r.y = wv.y * kDecay + acc[a][1] * kLrOverB;
        r.z = wv.z * kDecay + acc[a][2] * kLrOverB;
        r.w = wv.w * kDecay + acc[a][3] * kLrOverB;
        *reinterpret_cast<float4*>(W_out + base) = r;
    }
}

// ---------------------------------------------------------------------------
extern "C" void kernel_launch(void* const* d_in, const int* in_sizes, int n_in,
                              void* d_out, int out_size, void* d_ws, size_t ws_size,
                              hipStream_t stream)
{
    const float* x_t    = (const float*)d_in[0];
    const float* h_prev = (const float*)d_in[1];
    const float* W_ih   = (const float*)d_in[2];
    const float* b_ih   = (const float*)d_in[3];
    const float* W_f    = (const float*)d_in[4];
    const float* W_v    = (const float*)d_in[5];
    const float* gu     = (const float*)d_in[6];

    float* out    = (float*)d_out;
    float* h_next = out;                               // (B, H)
    float* W_out  = out + (size_t)B_DIM * H_DIM;       // (H, H)
    float* ic     = (float*)d_ws;                      // (B, H) scratch

    input_gemm<<<dim3(H_DIM / 64, B_DIM / 16), 256, 0, stream>>>(
        x_t, W_ih, b_ih, ic);

    fused_rows<<<dim3(H_DIM / 8, B_DIM / 8), 512, 0, stream>>>(
        h_prev, W_f, W_v, gu, ic, h_next);

    hebbian_update<<<dim3(H_DIM / 64, H_DIM / 64), 256, 0, stream>>>(
        h_next, h_prev, W_v, W_out);
}

// Round 3
// 162.130 us; speedup vs baseline: 1.0363x; 1.0363x over previous
//
#include <hip/hip_runtime.h>
#include <hip/hip_bf16.h>
#include <cstddef>

// Problem constants (reference: B=128, IN=1024, H=1024, TAU=1.0)
#define B_DIM  128
#define IN_DIM 1024
#define H_DIM  1024

constexpr float kDecay   = 1.0f - 0.01f;    // 1 - FAST_WEIGHT_DECAY
constexpr float kLrOverB = 0.01f / 128.0f;  // FAST_WEIGHT_LR / B

// ---------------------------------------------------------------------------
// Kernel E: E = exp(W_f + W_v), elementwise (1M floats).
// ---------------------------------------------------------------------------
__global__ __launch_bounds__(256) void exp_logits(
    const float* __restrict__ W_f,
    const float* __restrict__ W_v,
    float* __restrict__ E)
{
    const int i = blockIdx.x * 256 + threadIdx.x;  // float4 index, 262144 total
    const float4 a = reinterpret_cast<const float4*>(W_f)[i];
    const float4 b = reinterpret_cast<const float4*>(W_v)[i];
    float4 e;
    e.x = __expf(a.x + b.x); e.y = __expf(a.y + b.y);
    e.z = __expf(a.z + b.z); e.w = __expf(a.w + b.w);
    reinterpret_cast<float4*>(E)[i] = e;
}

// ---------------------------------------------------------------------------
// Kernel 0: ic[b][o] = x_t[b,:] . W_ih[o,:] + b_ih[o]     (268 MFLOP GEMM)
// ---------------------------------------------------------------------------
__global__ __launch_bounds__(256) void input_gemm(
    const float* __restrict__ x_t,   // (B, IN)
    const float* __restrict__ W_ih,  // (H, IN)
    const float* __restrict__ b_ih,  // (H,)
    float* __restrict__ ic)          // (B, H)  [workspace]
{
    const int o0 = blockIdx.x * 64;
    const int b0 = blockIdx.y * 16;
    const int t  = threadIdx.x;

    __shared__ float Wt[64][68];   // [k][o]
    __shared__ float xs[64][17];   // [k][b]

    const int tx = t & 15;         // o group: 4 outputs at o0 + 4*tx
    const int ty = t >> 4;         // b: b0 + ty

    float acc[4] = {0.f, 0.f, 0.f, 0.f};

    for (int kc = 0; kc < IN_DIM / 64; ++kc) {
        const int k0 = kc * 64;

#pragma unroll
        for (int ii = 0; ii < 4; ++ii) {
            const int i  = t + 256 * ii;
            const int r  = i >> 4;
            const int c4 = (i & 15) * 4;
            const float4 wv = *reinterpret_cast<const float4*>(
                &W_ih[(size_t)(o0 + r) * IN_DIM + k0 + c4]);
            Wt[c4 + 0][r] = wv.x; Wt[c4 + 1][r] = wv.y;
            Wt[c4 + 2][r] = wv.z; Wt[c4 + 3][r] = wv.w;
        }
        {
            const int br = t >> 4;
            const int c4 = (t & 15) * 4;
            const float4 xv = *reinterpret_cast<const float4*>(
                &x_t[(size_t)(b0 + br) * IN_DIM + k0 + c4]);
            xs[c4 + 0][br] = xv.x; xs[c4 + 1][br] = xv.y;
            xs[c4 + 2][br] = xv.z; xs[c4 + 3][br] = xv.w;
        }
        __syncthreads();

#pragma unroll 8
        for (int k = 0; k < 64; ++k) {
            const float  xb = xs[k][ty];
            const float4 wv = *reinterpret_cast<const float4*>(&Wt[k][4 * tx]);
            acc[0] = fmaf(wv.x, xb, acc[0]);
            acc[1] = fmaf(wv.y, xb, acc[1]);
            acc[2] = fmaf(wv.z, xb, acc[2]);
            acc[3] = fmaf(wv.w, xb, acc[3]);
        }
        __syncthreads();
    }

    const int o = o0 + 4 * tx;
    const int b = b0 + ty;
    float4 r;
    r.x = acc[0] + b_ih[o + 0];
    r.y = acc[1] + b_ih[o + 1];
    r.z = acc[2] + b_ih[o + 2];
    r.w = acc[3] + b_ih[o + 3];
    *reinterpret_cast<float4*>(&ic[(size_t)b * H_DIM + o]) = r;
}

// ---------------------------------------------------------------------------
// Kernel A: gumbel-softmax exchange + tanh. Pure-stream inner loop.
//   q_h  = exp(w_h) / (-ln u_h) ; dot/sum ratio invariant to the uniform
//   1/ln2 factor  ->  q'_h = E_h * rcp(-log2 u_h).
//   grid = (H/32, B), block = 256 (4 waves, no LDS, no barriers).
//   Wave w: b = blockIdx.y, rows o = blockIdx.x*32 + w*8 + (0..7) -> 32 KB
//   contiguous gumbel stream. Per-lane partials s[8], d[8]; ALL cross-lane
//   reductions deferred to one 16-chain ILP shuffle phase at the end.
// ---------------------------------------------------------------------------
__global__ __launch_bounds__(256) void fused_rows(
    const float* __restrict__ h_prev,  // (B, H)
    const float* __restrict__ E,       // (H, H) = exp(W_f+W_v)  [workspace]
    const float* __restrict__ gu,      // (B, H, H)
    const float* __restrict__ ic,      // (B, H)  [workspace, bias included]
    float* __restrict__ h_next)        // (B, H)  [= d_out region 0]
{
    const int b    = blockIdx.y;
    const int t    = threadIdx.x;
    const int w    = t >> 6;
    const int lane = t & 63;
    const int ob   = blockIdx.x * 32 + w * 8;   // first of this wave's 8 rows

    // h_prev row -> 16 registers (same row for all 4 waves: L1-friendly).
    const float4* hp4 = reinterpret_cast<const float4*>(h_prev + (size_t)b * H_DIM);
    float4 hp[4];
#pragma unroll
    for (int j = 0; j < 4; ++j) hp[j] = hp4[lane + 64 * j];

    const float4* g4 = reinterpret_cast<const float4*>(gu + ((size_t)b * H_DIM + ob) * H_DIM);
    const float4* e4 = reinterpret_cast<const float4*>(E + (size_t)ob * H_DIM);

    float s[8], d[8];

#pragma unroll
    for (int r = 0; r < 8; ++r) {
        float sum = 0.f, dot = 0.f;
#pragma unroll
        for (int j = 0; j < 4; ++j) {
            const int idx = r * 256 + lane + 64 * j;
            const float4 u = g4[idx];
            const float4 e = e4[idx];
            const float4 p = hp[j];

            const float q0 = __fdividef(e.x, -__log2f(fmaxf(u.x, 1e-9f)));
            const float q1 = __fdividef(e.y, -__log2f(fmaxf(u.y, 1e-9f)));
            const float q2 = __fdividef(e.z, -__log2f(fmaxf(u.z, 1e-9f)));
            const float q3 = __fdividef(e.w, -__log2f(fmaxf(u.w, 1e-9f)));

            sum += (q0 + q1) + (q2 + q3);
            dot = fmaf(q0, p.x, dot);
            dot = fmaf(q1, p.y, dot);
            dot = fmaf(q2, p.z, dot);
            dot = fmaf(q3, p.w, dot);
        }
        s[r] = sum;
        d[r] = dot;
    }

    // 16 independent xor-reduction chains (6 levels), high ILP.
#pragma unroll
    for (int off = 32; off > 0; off >>= 1) {
#pragma unroll
        for (int r = 0; r < 8; ++r) {
            s[r] += __shfl_xor(s[r], off, 64);
            d[r] += __shfl_xor(d[r], off, 64);
        }
    }

    if (lane == 0) {
        const size_t base = (size_t)b * H_DIM + ob;
        const float4 i0 = *reinterpret_cast<const float4*>(ic + base);
        const float4 i1 = *reinterpret_cast<const float4*>(ic + base + 4);
        float4 r0, r1;
        r0.x = tanhf(i0.x + __fdividef(d[0], s[0]));
        r0.y = tanhf(i0.y + __fdividef(d[1], s[1]));
        r0.z = tanhf(i0.z + __fdividef(d[2], s[2]));
        r0.w = tanhf(i0.w + __fdividef(d[3], s[3]));
        r1.x = tanhf(i1.x + __fdividef(d[4], s[4]));
        r1.y = tanhf(i1.y + __fdividef(d[5], s[5]));
        r1.z = tanhf(i1.z + __fdividef(d[6], s[6]));
        r1.w = tanhf(i1.w + __fdividef(d[7], s[7]));
        *reinterpret_cast<float4*>(h_next + base)     = r0;
        *reinterpret_cast<float4*>(h_next + base + 4) = r1;
    }
}

// ---------------------------------------------------------------------------
// Kernel B: W_out = 0.99 * W_v + (0.01/B) * (h_next^T @ h_prev)
// ---------------------------------------------------------------------------
__global__ __launch_bounds__(256) void hebbian_update(
    const float* __restrict__ h_next,  // (B, H)
    const float* __restrict__ h_prev,  // (B, H)
    const float* __restrict__ W_v,     // (H, H)
    float* __restrict__ W_out)         // (H, H)  [= d_out region 1]
{
    const int h0 = blockIdx.x * 64;
    const int o0 = blockIdx.y * 64;
    const int t  = threadIdx.x;

    __shared__ __align__(16) float hn_s[B_DIM][64];  // 32 KB
    __shared__ __align__(16) float hp_s[B_DIM][64];  // 32 KB

#pragma unroll
    for (int i = 0; i < 32; ++i) {
        const int e  = t + 256 * i;
        const int bb = e >> 6;
        const int cc = e & 63;
        hn_s[bb][cc] = h_next[(size_t)bb * H_DIM + o0 + cc];
        hp_s[bb][cc] = h_prev[(size_t)bb * H_DIM + h0 + cc];
    }
    __syncthreads();

    const int tx = t & 15;   // h group
    const int ty = t >> 4;   // o group

    float acc[4][4] = {{0.f}};

#pragma unroll 8
    for (int b = 0; b < B_DIM; ++b) {
        const float4 av = reinterpret_cast<const float4*>(hn_s[b])[ty];
        const float4 bv = reinterpret_cast<const float4*>(hp_s[b])[tx];
        const float aa[4] = {av.x, av.y, av.z, av.w};
        const float bb[4] = {bv.x, bv.y, bv.z, bv.w};
#pragma unroll
        for (int a = 0; a < 4; ++a)
#pragma unroll
            for (int c = 0; c < 4; ++c)
                acc[a][c] = fmaf(aa[a], bb[c], acc[a][c]);
    }

#pragma unroll
    for (int a = 0; a < 4; ++a) {
        const int o = o0 + 4 * ty + a;
        const size_t base = (size_t)o * H_DIM + h0 + 4 * tx;
        const float4 wv = *reinterpret_cast<const float4*>(W_v + base);
        float4 r;
        r.x = wv.x * kDecay + acc[a][0] * kLrOverB;
        r.y = wv.y * kDecay + acc[a][1] * kLrOverB;
        r.z = wv.z * kDecay + acc[a][2] * kLrOverB;
        r.w = wv.w * kDecay + acc[a][3] * kLrOverB;
        *reinterpret_cast<float4*>(W_out + base) = r;
    }
}

// ---------------------------------------------------------------------------
extern "C" void kernel_launch(void* const* d_in, const int* in_sizes, int n_in,
                              void* d_out, int out_size, void* d_ws, size_t ws_size,
                              hipStream_t stream)
{
    const float* x_t    = (const float*)d_in[0];
    const float* h_prev = (const float*)d_in[1];
    const float* W_ih   = (const float*)d_in[2];
    const float* b_ih   = (const float*)d_in[3];
    const float* W_f    = (const float*)d_in[4];
    const float* W_v    = (const float*)d_in[5];
    const float* gu     = (const float*)d_in[6];

    float* out    = (float*)d_out;
    float* h_next = out;                               // (B, H)
    float* W_out  = out + (size_t)B_DIM * H_DIM;       // (H, H)

    float* E  = (float*)d_ws;                          // (H, H)  4 MB
    float* ic = E + (size_t)H_DIM * H_DIM;             // (B, H)  0.5 MB

    exp_logits<<<dim3(H_DIM * H_DIM / 1024), 256, 0, stream>>>(W_f, W_v, E);

    input_gemm<<<dim3(H_DIM / 64, B_DIM / 16), 256, 0, stream>>>(
        x_t, W_ih, b_ih, ic);

    fused_rows<<<dim3(H_DIM / 32, B_DIM), 256, 0, stream>>>(
        h_prev, E, gu, ic, h_next);

    hebbian_update<<<dim3(H_DIM / 64, H_DIM / 64), 256, 0, stream>>>(
        h_next, h_prev, W_v, W_out);
}

// Round 5
// 154.853 us; speedup vs baseline: 1.0850x; 1.0470x over previous
//
#include <hip/hip_runtime.h>
#include <hip/hip_bf16.h>
#include <cstddef>

// Problem constants (reference: B=128, IN=1024, H=1024, TAU=1.0)
#define B_DIM  128
#define IN_DIM 1024
#define H_DIM  1024

constexpr float kDecay   = 1.0f - 0.01f;    // 1 - FAST_WEIGHT_DECAY
constexpr float kLrOverB = 0.01f / 128.0f;  // FAST_WEIGHT_LR / B

// Native clang vector type: __builtin_nontemporal_load needs this (it rejects
// HIP_vector_type<float,4>*). Same 16-byte layout as float4.
typedef float f32x4 __attribute__((ext_vector_type(4)));

// ---------------------------------------------------------------------------
// Kernel E: E = exp(W_f + W_v), elementwise (1M floats).
// ---------------------------------------------------------------------------
__global__ __launch_bounds__(256) void exp_logits(
    const float* __restrict__ W_f,
    const float* __restrict__ W_v,
    float* __restrict__ E)
{
    const int i = blockIdx.x * 256 + threadIdx.x;  // float4 index, 262144 total
    const float4 a = reinterpret_cast<const float4*>(W_f)[i];
    const float4 b = reinterpret_cast<const float4*>(W_v)[i];
    float4 e;
    e.x = __expf(a.x + b.x); e.y = __expf(a.y + b.y);
    e.z = __expf(a.z + b.z); e.w = __expf(a.w + b.w);
    reinterpret_cast<float4*>(E)[i] = e;
}

// ---------------------------------------------------------------------------
// Kernel 0: ic[b][o] = x_t[b,:] . W_ih[o,:] + b_ih[o]     (268 MFLOP GEMM)
// ---------------------------------------------------------------------------
__global__ __launch_bounds__(256) void input_gemm(
    const float* __restrict__ x_t,   // (B, IN)
    const float* __restrict__ W_ih,  // (H, IN)
    const float* __restrict__ b_ih,  // (H,)
    float* __restrict__ ic)          // (B, H)  [workspace]
{
    const int o0 = blockIdx.x * 64;
    const int b0 = blockIdx.y * 16;
    const int t  = threadIdx.x;

    __shared__ float Wt[64][68];   // [k][o]
    __shared__ float xs[64][17];   // [k][b]

    const int tx = t & 15;         // o group: 4 outputs at o0 + 4*tx
    const int ty = t >> 4;         // b: b0 + ty

    float acc[4] = {0.f, 0.f, 0.f, 0.f};

    for (int kc = 0; kc < IN_DIM / 64; ++kc) {
        const int k0 = kc * 64;

#pragma unroll
        for (int ii = 0; ii < 4; ++ii) {
            const int i  = t + 256 * ii;
            const int r  = i >> 4;
            const int c4 = (i & 15) * 4;
            const float4 wv = *reinterpret_cast<const float4*>(
                &W_ih[(size_t)(o0 + r) * IN_DIM + k0 + c4]);
            Wt[c4 + 0][r] = wv.x; Wt[c4 + 1][r] = wv.y;
            Wt[c4 + 2][r] = wv.z; Wt[c4 + 3][r] = wv.w;
        }
        {
            const int br = t >> 4;
            const int c4 = (t & 15) * 4;
            const float4 xv = *reinterpret_cast<const float4*>(
                &x_t[(size_t)(b0 + br) * IN_DIM + k0 + c4]);
            xs[c4 + 0][br] = xv.x; xs[c4 + 1][br] = xv.y;
            xs[c4 + 2][br] = xv.z; xs[c4 + 3][br] = xv.w;
        }
        __syncthreads();

#pragma unroll 8
        for (int k = 0; k < 64; ++k) {
            const float  xb = xs[k][ty];
            const float4 wv = *reinterpret_cast<const float4*>(&Wt[k][4 * tx]);
            acc[0] = fmaf(wv.x, xb, acc[0]);
            acc[1] = fmaf(wv.y, xb, acc[1]);
            acc[2] = fmaf(wv.z, xb, acc[2]);
            acc[3] = fmaf(wv.w, xb, acc[3]);
        }
        __syncthreads();
    }

    const int o = o0 + 4 * tx;
    const int b = b0 + ty;
    float4 r;
    r.x = acc[0] + b_ih[o + 0];
    r.y = acc[1] + b_ih[o + 1];
    r.z = acc[2] + b_ih[o + 2];
    r.w = acc[3] + b_ih[o + 3];
    *reinterpret_cast<float4*>(&ic[(size_t)b * H_DIM + o]) = r;
}

// ---------------------------------------------------------------------------
// Kernel A (v4b): gumbel-softmax exchange + tanh.
//   SINGLE global stream design: per inner iteration the ONLY global loads
//   are 16 contiguous nontemporal float4 gumbel loads (16 KB per wave in
//   flight). E rows live in 64 VGPRs (loaded once per wave, reused x8 b's);
//   h_prev chunk lives in LDS (ds_read_b128, reused x4 rows per read).
//   grid = (B/8, H/16)  [x = b-chunk fastest so consecutive blocks share the
//   same E rows -> XCD L2 locality]; block = 256 (4 waves).
//   Wave w owns rows orow0 = oc*16 + w*4 .. +3 for 8 b's.
// ---------------------------------------------------------------------------
__global__ __launch_bounds__(256) void fused_rows(
    const float* __restrict__ h_prev,  // (B, H)
    const float* __restrict__ E,       // (H, H) = exp(W_f+W_v)  [workspace]
    const float* __restrict__ gu,      // (B, H, H)
    const float* __restrict__ ic,      // (B, H)  [workspace, bias included]
    float* __restrict__ h_next)        // (B, H)  [= d_out region 0]
{
    const int b0 = blockIdx.x * 8;
    const int o0 = blockIdx.y * 16;
    const int t  = threadIdx.x;
    const int w  = t >> 6, lane = t & 63;

    __shared__ __align__(16) float hp_s[8 * H_DIM];  // 32 KB

    // Stage h_prev rows b0..b0+7 (2048 float4 by 256 threads).
    {
        const float4* src = reinterpret_cast<const float4*>(h_prev) + (size_t)b0 * 256;
        float4*       dst = reinterpret_cast<float4*>(hp_s);
#pragma unroll
        for (int ii = 0; ii < 8; ++ii) dst[t + 256 * ii] = src[t + 256 * ii];
    }
    __syncthreads();

    const int orow0 = o0 + w * 4;

    // E rows -> 64 registers, reused for all 8 b's.
    float4 e[4][4];
    {
        const float4* E4 = reinterpret_cast<const float4*>(E) + (size_t)orow0 * 256;
#pragma unroll
        for (int r = 0; r < 4; ++r)
#pragma unroll
            for (int j = 0; j < 4; ++j)
                e[r][j] = E4[r * 256 + lane + 64 * j];
    }

    const float4* hp4 = reinterpret_cast<const float4*>(hp_s);

    for (int bb = 0; bb < 8; ++bb) {
        const int b = b0 + bb;
        const f32x4* g4 = reinterpret_cast<const f32x4*>(gu)
                        + ((size_t)b * H_DIM + orow0) * 256;

        // Phase 1: issue all 16 KB of this (wave, b) tile's loads (nontemporal:
        // one-touch stream, keep E/hp resident in L2/L3).
        f32x4 u[4][4];
#pragma unroll
        for (int r = 0; r < 4; ++r)
#pragma unroll
            for (int j = 0; j < 4; ++j)
                u[r][j] = __builtin_nontemporal_load(g4 + (r * 4 + j) * 64 + lane);

        // h_prev fragments from LDS (reused across the 4 rows).
        float4 p[4];
#pragma unroll
        for (int j = 0; j < 4; ++j) p[j] = hp4[bb * 256 + lane + 64 * j];

        // Phase 2: compute per-lane partials for 4 rows.
        float s[4], d[4];
#pragma unroll
        for (int r = 0; r < 4; ++r) {
            float sum = 0.f, dot = 0.f;
#pragma unroll
            for (int j = 0; j < 4; ++j) {
                const f32x4 uu = u[r][j];
                const float4 ee = e[r][j];
                const float4 pp = p[j];
                const float q0 = __fdividef(ee.x, -__log2f(fmaxf(uu.x, 1e-9f)));
                const float q1 = __fdividef(ee.y, -__log2f(fmaxf(uu.y, 1e-9f)));
                const float q2 = __fdividef(ee.z, -__log2f(fmaxf(uu.z, 1e-9f)));
                const float q3 = __fdividef(ee.w, -__log2f(fmaxf(uu.w, 1e-9f)));
                sum += (q0 + q1) + (q2 + q3);
                dot = fmaf(q0, pp.x, dot);
                dot = fmaf(q1, pp.y, dot);
                dot = fmaf(q2, pp.z, dot);
                dot = fmaf(q3, pp.w, dot);
            }
            s[r] = sum;
            d[r] = dot;
        }

        // 8 independent xor-reduction chains (deferred, high ILP).
#pragma unroll
        for (int off = 32; off > 0; off >>= 1) {
#pragma unroll
            for (int r = 0; r < 4; ++r) {
                s[r] += __shfl_xor(s[r], off, 64);
                d[r] += __shfl_xor(d[r], off, 64);
            }
        }

        if (lane == 0) {
#pragma unroll
            for (int r = 0; r < 4; ++r) {
                const size_t idx = (size_t)b * H_DIM + orow0 + r;
                h_next[idx] = tanhf(ic[idx] + __fdividef(d[r], s[r]));
            }
        }
    }
}

// ---------------------------------------------------------------------------
// Kernel B: W_out = 0.99 * W_v + (0.01/B) * (h_next^T @ h_prev)
// ---------------------------------------------------------------------------
__global__ __launch_bounds__(256) void hebbian_update(
    const float* __restrict__ h_next,  // (B, H)
    const float* __restrict__ h_prev,  // (B, H)
    const float* __restrict__ W_v,     // (H, H)
    float* __restrict__ W_out)         // (H, H)  [= d_out region 1]
{
    const int h0 = blockIdx.x * 64;
    const int o0 = blockIdx.y * 64;
    const int t  = threadIdx.x;

    __shared__ __align__(16) float hn_s[B_DIM][64];  // 32 KB
    __shared__ __align__(16) float hp_s[B_DIM][64];  // 32 KB

#pragma unroll
    for (int i = 0; i < 32; ++i) {
        const int e  = t + 256 * i;
        const int bb = e >> 6;
        const int cc = e & 63;
        hn_s[bb][cc] = h_next[(size_t)bb * H_DIM + o0 + cc];
        hp_s[bb][cc] = h_prev[(size_t)bb * H_DIM + h0 + cc];
    }
    __syncthreads();

    const int tx = t & 15;   // h group
    const int ty = t >> 4;   // o group

    float acc[4][4] = {{0.f}};

#pragma unroll 8
    for (int b = 0; b < B_DIM; ++b) {
        const float4 av = reinterpret_cast<const float4*>(hn_s[b])[ty];
        const float4 bv = reinterpret_cast<const float4*>(hp_s[b])[tx];
        const float aa[4] = {av.x, av.y, av.z, av.w};
        const float bb[4] = {bv.x, bv.y, bv.z, bv.w};
#pragma unroll
        for (int a = 0; a < 4; ++a)
#pragma unroll
            for (int c = 0; c < 4; ++c)
                acc[a][c] = fmaf(aa[a], bb[c], acc[a][c]);
    }

#pragma unroll
    for (int a = 0; a < 4; ++a) {
        const int o = o0 + 4 * ty + a;
        const size_t base = (size_t)o * H_DIM + h0 + 4 * tx;
        const float4 wv = *reinterpret_cast<const float4*>(W_v + base);
        float4 r;
        r.x = wv.x * kDecay + acc[a][0] * kLrOverB;
        r.y = wv.y * kDecay + acc[a][1] * kLrOverB;
        r.z = wv.z * kDecay + acc[a][2] * kLrOverB;
        r.w = wv.w * kDecay + acc[a][3] * kLrOverB;
        *reinterpret_cast<float4*>(W_out + base) = r;
    }
}

// ---------------------------------------------------------------------------
extern "C" void kernel_launch(void* const* d_in, const int* in_sizes, int n_in,
                              void* d_out, int out_size, void* d_ws, size_t ws_size,
                              hipStream_t stream)
{
    const float* x_t    = (const float*)d_in[0];
    const float* h_prev = (const float*)d_in[1];
    const float* W_ih   = (const float*)d_in[2];
    const float* b_ih   = (const float*)d_in[3];
    const float* W_f    = (const float*)d_in[4];
    const float* W_v    = (const float*)d_in[5];
    const float* gu     = (const float*)d_in[6];

    float* out    = (float*)d_out;
    float* h_next = out;                               // (B, H)
    float* W_out  = out + (size_t)B_DIM * H_DIM;       // (H, H)

    float* E  = (float*)d_ws;                          // (H, H)  4 MB
    float* ic = E + (size_t)H_DIM * H_DIM;             // (B, H)  0.5 MB

    exp_logits<<<dim3(H_DIM * H_DIM / 1024), 256, 0, stream>>>(W_f, W_v, E);

    input_gemm<<<dim3(H_DIM / 64, B_DIM / 16), 256, 0, stream>>>(
        x_t, W_ih, b_ih, ic);

    fused_rows<<<dim3(B_DIM / 8, H_DIM / 16), 256, 0, stream>>>(
        h_prev, E, gu, ic, h_next);

    hebbian_update<<<dim3(H_DIM / 64, H_DIM / 64), 256, 0, stream>>>(
        h_next, h_prev, W_v, W_out);
}

// Round 6
// 144.121 us; speedup vs baseline: 1.1658x; 1.0745x over previous
//
#include <hip/hip_runtime.h>
#include <hip/hip_bf16.h>
#include <cstddef>

// Problem constants (reference: B=128, IN=1024, H=1024, TAU=1.0)
#define B_DIM  128
#define IN_DIM 1024
#define H_DIM  1024

constexpr float kDecay   = 1.0f - 0.01f;    // 1 - FAST_WEIGHT_DECAY
constexpr float kLrOverB = 0.01f / 128.0f;  // FAST_WEIGHT_LR / B

// Native clang vector type: __builtin_nontemporal_load needs this.
typedef float f32x4 __attribute__((ext_vector_type(4)));

// ---------------------------------------------------------------------------
// Kernel E: E = exp(W_f + W_v), elementwise (1M floats).
// ---------------------------------------------------------------------------
__global__ __launch_bounds__(256) void exp_logits(
    const float* __restrict__ W_f,
    const float* __restrict__ W_v,
    float* __restrict__ E)
{
    const int i = blockIdx.x * 256 + threadIdx.x;  // float4 index, 262144 total
    const float4 a = reinterpret_cast<const float4*>(W_f)[i];
    const float4 b = reinterpret_cast<const float4*>(W_v)[i];
    float4 e;
    e.x = __expf(a.x + b.x); e.y = __expf(a.y + b.y);
    e.z = __expf(a.z + b.z); e.w = __expf(a.w + b.w);
    reinterpret_cast<float4*>(E)[i] = e;
}

// ---------------------------------------------------------------------------
// Kernel 0: ic[b][o] = x_t[b,:] . W_ih[o,:] + b_ih[o]     (268 MFLOP GEMM)
// ---------------------------------------------------------------------------
__global__ __launch_bounds__(256) void input_gemm(
    const float* __restrict__ x_t,   // (B, IN)
    const float* __restrict__ W_ih,  // (H, IN)
    const float* __restrict__ b_ih,  // (H,)
    float* __restrict__ ic)          // (B, H)  [workspace]
{
    const int o0 = blockIdx.x * 64;
    const int b0 = blockIdx.y * 16;
    const int t  = threadIdx.x;

    __shared__ float Wt[64][68];   // [k][o]
    __shared__ float xs[64][17];   // [k][b]

    const int tx = t & 15;         // o group: 4 outputs at o0 + 4*tx
    const int ty = t >> 4;         // b: b0 + ty

    float acc[4] = {0.f, 0.f, 0.f, 0.f};

    for (int kc = 0; kc < IN_DIM / 64; ++kc) {
        const int k0 = kc * 64;

#pragma unroll
        for (int ii = 0; ii < 4; ++ii) {
            const int i  = t + 256 * ii;
            const int r  = i >> 4;
            const int c4 = (i & 15) * 4;
            const float4 wv = *reinterpret_cast<const float4*>(
                &W_ih[(size_t)(o0 + r) * IN_DIM + k0 + c4]);
            Wt[c4 + 0][r] = wv.x; Wt[c4 + 1][r] = wv.y;
            Wt[c4 + 2][r] = wv.z; Wt[c4 + 3][r] = wv.w;
        }
        {
            const int br = t >> 4;
            const int c4 = (t & 15) * 4;
            const float4 xv = *reinterpret_cast<const float4*>(
                &x_t[(size_t)(b0 + br) * IN_DIM + k0 + c4]);
            xs[c4 + 0][br] = xv.x; xs[c4 + 1][br] = xv.y;
            xs[c4 + 2][br] = xv.z; xs[c4 + 3][br] = xv.w;
        }
        __syncthreads();

#pragma unroll 8
        for (int k = 0; k < 64; ++k) {
            const float  xb = xs[k][ty];
            const float4 wv = *reinterpret_cast<const float4*>(&Wt[k][4 * tx]);
            acc[0] = fmaf(wv.x, xb, acc[0]);
            acc[1] = fmaf(wv.y, xb, acc[1]);
            acc[2] = fmaf(wv.z, xb, acc[2]);
            acc[3] = fmaf(wv.w, xb, acc[3]);
        }
        __syncthreads();
    }

    const int o = o0 + 4 * tx;
    const int b = b0 + ty;
    float4 r;
    r.x = acc[0] + b_ih[o + 0];
    r.y = acc[1] + b_ih[o + 1];
    r.z = acc[2] + b_ih[o + 2];
    r.w = acc[3] + b_ih[o + 3];
    *reinterpret_cast<float4*>(&ic[(size_t)b * H_DIM + o]) = r;
}

// ---------------------------------------------------------------------------
// Kernel A (v5): gumbel-softmax exchange + tanh.
//   Low-VGPR (<=128, 4 waves/SIMD) + 2-deep register double-buffer so every
//   wave keeps a 4 KB tile in flight continuously.
//   grid = (B/4, H/8), block = 256 (4 waves).
//   Wave w owns b = b0 + w: h_prev[b] fragment persistent in 16 VGPRs;
//   loops over 8 consecutive o-rows (32 KB contiguous nontemporal gumbel).
//   E rows o0..o0+7 staged once per block in 32 KB LDS (shared by 4 waves).
//   s[8], d[8] partials; all cross-lane reduction deferred to one phase.
// ---------------------------------------------------------------------------
__global__ __launch_bounds__(256, 4) void fused_rows(
    const float* __restrict__ h_prev,  // (B, H)
    const float* __restrict__ E,       // (H, H) = exp(W_f+W_v)  [workspace]
    const float* __restrict__ gu,      // (B, H, H)
    const float* __restrict__ ic,      // (B, H)  [workspace, bias included]
    float* __restrict__ h_next)        // (B, H)  [= d_out region 0]
{
    const int b0 = blockIdx.x * 4;
    const int o0 = blockIdx.y * 8;
    const int t  = threadIdx.x;
    const int w  = t >> 6, lane = t & 63;

    __shared__ __align__(16) float e_s[8 * H_DIM];  // 32 KB: E rows o0..o0+7

    {
        const float4* src = reinterpret_cast<const float4*>(E) + (size_t)o0 * 256;
        float4*       dst = reinterpret_cast<float4*>(e_s);
#pragma unroll
        for (int ii = 0; ii < 8; ++ii) dst[t + 256 * ii] = src[t + 256 * ii];
    }
    __syncthreads();

    const int b = b0 + w;

    // h_prev[b] fragment -> 16 persistent VGPRs (same for all 8 o-rows).
    const float4* hp4 = reinterpret_cast<const float4*>(h_prev + (size_t)b * H_DIM);
    float4 p[4];
#pragma unroll
    for (int j = 0; j < 4; ++j) p[j] = hp4[lane + 64 * j];

    const f32x4*  g4 = reinterpret_cast<const f32x4*>(gu)
                     + ((size_t)b * H_DIM + o0) * 256;
    const float4* e4 = reinterpret_cast<const float4*>(e_s);

    f32x4 ua[4], ub[4];
    float s[8], d[8];

    // Prologue: tile 0 into ua.
#pragma unroll
    for (int j = 0; j < 4; ++j)
        ua[j] = __builtin_nontemporal_load(g4 + lane + 64 * j);

#pragma unroll
    for (int oi = 0; oi < 8; ++oi) {
        // Prefetch tile oi+1 into the buffer not being consumed (static idx).
        if (oi < 7) {
            const f32x4* gn = g4 + (size_t)(oi + 1) * 256;
            if ((oi & 1) == 0) {
#pragma unroll
                for (int j = 0; j < 4; ++j)
                    ub[j] = __builtin_nontemporal_load(gn + lane + 64 * j);
            } else {
#pragma unroll
                for (int j = 0; j < 4; ++j)
                    ua[j] = __builtin_nontemporal_load(gn + lane + 64 * j);
            }
        }

        float sum = 0.f, dot = 0.f;
#pragma unroll
        for (int j = 0; j < 4; ++j) {
            const f32x4  uu = (oi & 1) ? ub[j] : ua[j];
            const float4 ee = e4[oi * 256 + lane + 64 * j];
            const float4 pp = p[j];
            const float q0 = __fdividef(ee.x, -__log2f(fmaxf(uu.x, 1e-9f)));
            const float q1 = __fdividef(ee.y, -__log2f(fmaxf(uu.y, 1e-9f)));
            const float q2 = __fdividef(ee.z, -__log2f(fmaxf(uu.z, 1e-9f)));
            const float q3 = __fdividef(ee.w, -__log2f(fmaxf(uu.w, 1e-9f)));
            sum += (q0 + q1) + (q2 + q3);
            dot = fmaf(q0, pp.x, dot);
            dot = fmaf(q1, pp.y, dot);
            dot = fmaf(q2, pp.z, dot);
            dot = fmaf(q3, pp.w, dot);
        }
        s[oi] = sum;
        d[oi] = dot;
    }

    // 16 independent xor-reduction chains (deferred, high ILP).
#pragma unroll
    for (int off = 32; off > 0; off >>= 1) {
#pragma unroll
        for (int r = 0; r < 8; ++r) {
            s[r] += __shfl_xor(s[r], off, 64);
            d[r] += __shfl_xor(d[r], off, 64);
        }
    }

    if (lane == 0) {
        const size_t base = (size_t)b * H_DIM + o0;
        const float4 i0 = *reinterpret_cast<const float4*>(ic + base);
        const float4 i1 = *reinterpret_cast<const float4*>(ic + base + 4);
        float4 r0, r1;
        r0.x = tanhf(i0.x + __fdividef(d[0], s[0]));
        r0.y = tanhf(i0.y + __fdividef(d[1], s[1]));
        r0.z = tanhf(i0.z + __fdividef(d[2], s[2]));
        r0.w = tanhf(i0.w + __fdividef(d[3], s[3]));
        r1.x = tanhf(i1.x + __fdividef(d[4], s[4]));
        r1.y = tanhf(i1.y + __fdividef(d[5], s[5]));
        r1.z = tanhf(i1.z + __fdividef(d[6], s[6]));
        r1.w = tanhf(i1.w + __fdividef(d[7], s[7]));
        *reinterpret_cast<float4*>(h_next + base)     = r0;
        *reinterpret_cast<float4*>(h_next + base + 4) = r1;
    }
}

// ---------------------------------------------------------------------------
// Kernel B: W_out = 0.99 * W_v + (0.01/B) * (h_next^T @ h_prev)
// ---------------------------------------------------------------------------
__global__ __launch_bounds__(256) void hebbian_update(
    const float* __restrict__ h_next,  // (B, H)
    const float* __restrict__ h_prev,  // (B, H)
    const float* __restrict__ W_v,     // (H, H)
    float* __restrict__ W_out)         // (H, H)  [= d_out region 1]
{
    const int h0 = blockIdx.x * 64;
    const int o0 = blockIdx.y * 64;
    const int t  = threadIdx.x;

    __shared__ __align__(16) float hn_s[B_DIM][64];  // 32 KB
    __shared__ __align__(16) float hp_s[B_DIM][64];  // 32 KB

#pragma unroll
    for (int i = 0; i < 32; ++i) {
        const int e  = t + 256 * i;
        const int bb = e >> 6;
        const int cc = e & 63;
        hn_s[bb][cc] = h_next[(size_t)bb * H_DIM + o0 + cc];
        hp_s[bb][cc] = h_prev[(size_t)bb * H_DIM + h0 + cc];
    }
    __syncthreads();

    const int tx = t & 15;   // h group
    const int ty = t >> 4;   // o group

    float acc[4][4] = {{0.f}};

#pragma unroll 8
    for (int b = 0; b < B_DIM; ++b) {
        const float4 av = reinterpret_cast<const float4*>(hn_s[b])[ty];
        const float4 bv = reinterpret_cast<const float4*>(hp_s[b])[tx];
        const float aa[4] = {av.x, av.y, av.z, av.w};
        const float bb[4] = {bv.x, bv.y, bv.z, bv.w};
#pragma unroll
        for (int a = 0; a < 4; ++a)
#pragma unroll
            for (int c = 0; c < 4; ++c)
                acc[a][c] = fmaf(aa[a], bb[c], acc[a][c]);
    }

#pragma unroll
    for (int a = 0; a < 4; ++a) {
        const int o = o0 + 4 * ty + a;
        const size_t base = (size_t)o * H_DIM + h0 + 4 * tx;
        const float4 wv = *reinterpret_cast<const float4*>(W_v + base);
        float4 r;
        r.x = wv.x * kDecay + acc[a][0] * kLrOverB;
        r.y = wv.y * kDecay + acc[a][1] * kLrOverB;
        r.z = wv.z * kDecay + acc[a][2] * kLrOverB;
        r.w = wv.w * kDecay + acc[a][3] * kLrOverB;
        *reinterpret_cast<float4*>(W_out + base) = r;
    }
}

// ---------------------------------------------------------------------------
extern "C" void kernel_launch(void* const* d_in, const int* in_sizes, int n_in,
                              void* d_out, int out_size, void* d_ws, size_t ws_size,
                              hipStream_t stream)
{
    const float* x_t    = (const float*)d_in[0];
    const float* h_prev = (const float*)d_in[1];
    const float* W_ih   = (const float*)d_in[2];
    const float* b_ih   = (const float*)d_in[3];
    const float* W_f    = (const float*)d_in[4];
    const float* W_v    = (const float*)d_in[5];
    const float* gu     = (const float*)d_in[6];

    float* out    = (float*)d_out;
    float* h_next = out;                               // (B, H)
    float* W_out  = out + (size_t)B_DIM * H_DIM;       // (H, H)

    float* E  = (float*)d_ws;                          // (H, H)  4 MB
    float* ic = E + (size_t)H_DIM * H_DIM;             // (B, H)  0.5 MB

    exp_logits<<<dim3(H_DIM * H_DIM / 1024), 256, 0, stream>>>(W_f, W_v, E);

    input_gemm<<<dim3(H_DIM / 64, B_DIM / 16), 256, 0, stream>>>(
        x_t, W_ih, b_ih, ic);

    fused_rows<<<dim3(B_DIM / 4, H_DIM / 8), 256, 0, stream>>>(
        h_prev, E, gu, ic, h_next);

    hebbian_update<<<dim3(H_DIM / 64, H_DIM / 64), 256, 0, stream>>>(
        h_next, h_prev, W_v, W_out);
}